// Round 11
// baseline (441.864 us; speedup 1.0000x reference)
//
#include <hip/hip_runtime.h>

typedef __bf16 bf16x8 __attribute__((ext_vector_type(8)));
typedef float f32x4 __attribute__((ext_vector_type(4)));

#define CHUNK 4096
#define NBUCK 512

struct WPack { const float* p[9]; };

__device__ inline __bf16 f2bf(float f){ return (__bf16)f; }

// Swizzled 64x128 bf16 LDS tile (16KB, no pad). Element (r,c) lives at
// r*128 + (((c>>3) ^ (r&7))<<3) + (c&7).
__device__ inline int hswz(int r, int c){
  return (r << 7) + ((((c >> 3) ^ (r & 7)) << 3) | (c & 7));
}
__device__ inline const __bf16* hvec(const __bf16* H, int r, int g){  // g = 8-elem granule 0..15
  return H + (r << 7) + (((g ^ (r & 7)) & 15) << 3);
}

// Combined prep: blocks [0,576) convert 9 fp32 128x128 weight mats into MFMA
// B-fragment layout (bf16); blocks [576,...) bulk-convert x fp32->bf16.
__global__ __launch_bounds__(256) void prep_kernel(WPack pk, __bf16* __restrict__ wf,
    const float* __restrict__ x, __bf16* __restrict__ xb, int n8){
  int b = blockIdx.x, t = threadIdx.x;
  if (b < 576){
    int tid = b*256 + t;
    int m = tid >> 14;
    int r = tid & 16383;
    int j = r & 7;
    int lane = (r >> 3) & 63;
    int ks = (r >> 9) & 3;
    int c = r >> 11;
    int k = ks*32 + ((lane>>4)<<3) + j;
    int col = (c<<4) + (lane & 15);
    wf[tid] = f2bf(pk.p[m][k*128 + col]);
  } else {
    int i = (b - 576)*256 + t;
    if (i >= n8) return;
    f32x4 a = ((const f32x4*)x)[2*i];
    f32x4 bb = ((const f32x4*)x)[2*i+1];
    bf16x8 r;
    r[0]=f2bf(a[0]); r[1]=f2bf(a[1]); r[2]=f2bf(a[2]); r[3]=f2bf(a[3]);
    r[4]=f2bf(bb[0]); r[5]=f2bf(bb[1]); r[6]=f2bf(bb[2]); r[7]=f2bf(bb[3]);
    ((bf16x8*)xb)[i] = r;
  }
}

// ---- CSR build via two-level bucket sort (no global atomics) ----
__global__ __launch_bounds__(256) void p1_count(const int* __restrict__ ei, int E, int NBLK,
    int* __restrict__ cnt){
  __shared__ int h[NBUCK];
  int b = blockIdx.x, t = threadIdx.x;
  h[t] = 0; h[t + 256] = 0;
  __syncthreads();
  int base = b*CHUNK;
  int lim = E - base; if (lim > CHUNK) lim = CHUNK;
  for (int i = t; i < lim; i += 256)
    atomicAdd(&h[ei[E + base + i] >> 8], 1);     // dst row
  __syncthreads();
  cnt[t*NBLK + b] = h[t];
  cnt[(t + 256)*NBLK + b] = h[t + 256];
}

__global__ __launch_bounds__(256) void scan1_kernel(const int* __restrict__ cnt, int* __restrict__ bsum, int L){
  __shared__ int sh[256];
  int b = blockIdx.x, t = threadIdx.x;
  int base = b*2048 + t*8;
  int s = 0;
  #pragma unroll
  for (int j = 0; j < 8; j++){ int i = base + j; if (i < L) s += cnt[i]; }
  sh[t] = s; __syncthreads();
  for (int off = 128; off > 0; off >>= 1){
    if (t < off) sh[t] += sh[t + off];
    __syncthreads();
  }
  if (t == 0) bsum[b] = sh[0];
}

__global__ __launch_bounds__(256) void scan2_kernel(const int* __restrict__ bsum, int* __restrict__ boff,
                                                    int NB, int* __restrict__ total_out){
  __shared__ int sh[256];
  int t = threadIdx.x;
  int v = (t < NB) ? bsum[t] : 0;
  sh[t] = v; __syncthreads();
  for (int off = 1; off < 256; off <<= 1){
    int u = (t >= off) ? sh[t - off] : 0;
    __syncthreads();
    sh[t] += u;
    __syncthreads();
  }
  if (t < NB) boff[t] = sh[t] - v;          // exclusive
  if (t == 255) *total_out = sh[255];       // rs[N] = E
}

__global__ __launch_bounds__(256) void scan3_kernel(const int* __restrict__ cnt, const int* __restrict__ boff,
                                                    int* __restrict__ off, int L){
  __shared__ int sh[256];
  int b = blockIdx.x, t = threadIdx.x;
  int base = b*2048 + t*8;
  int loc[8]; int s = 0;
  #pragma unroll
  for (int j = 0; j < 8; j++){ int i = base + j; int d = (i < L) ? cnt[i] : 0; loc[j] = d; s += d; }
  sh[t] = s; __syncthreads();
  for (int o = 1; o < 256; o <<= 1){
    int u = (t >= o) ? sh[t - o] : 0;
    __syncthreads();
    sh[t] += u;
    __syncthreads();
  }
  int excl = boff[b] + sh[t] - s;
  #pragma unroll
  for (int j = 0; j < 8; j++){ int i = base + j; if (i < L) off[i] = excl; excl += loc[j]; }
}

__global__ __launch_bounds__(256) void p3_scatter(const int* __restrict__ ei, int E, int NBLK,
    const int* __restrict__ off, int* __restrict__ tpack){
  __shared__ int cur[NBUCK];
  int b = blockIdx.x, t = threadIdx.x;
  cur[t]       = off[t*NBLK + b];
  cur[t + 256] = off[(t + 256)*NBLK + b];
  __syncthreads();
  int base = b*CHUNK;
  int lim = E - base; if (lim > CHUNK) lim = CHUNK;
  for (int i = t; i < lim; i += 256){
    int s = ei[base + i];
    int d = ei[E + base + i];
    int p = atomicAdd(&cur[d >> 8], 1);   // LDS atomic: global slot
    tpack[p] = (s << 8) | (d & 255);
  }
}

__global__ __launch_bounds__(256) void p4_build(const int* __restrict__ tpack,
    const int* __restrict__ off, int NBLK, int E, int N,
    int* __restrict__ rs, int* __restrict__ csr){
  __shared__ int dc[256], sc[256];
  int q = blockIdx.x, t = threadIdx.x;
  int bstart = off[q*NBLK];
  int bend = (q == NBUCK-1) ? E : off[(q+1)*NBLK];
  dc[t] = 0;
  __syncthreads();
  for (int i = bstart + t; i < bend; i += 256)
    atomicAdd(&dc[tpack[i] & 255], 1);
  __syncthreads();
  int v = dc[t];
  sc[t] = v; __syncthreads();
  for (int o = 1; o < 256; o <<= 1){
    int u = (t >= o) ? sc[t - o] : 0;
    __syncthreads();
    sc[t] += u;
    __syncthreads();
  }
  int ex = sc[t] - v;                  // exclusive within bucket
  int gd = q*256 + t;
  if (gd < N) rs[gd] = bstart + ex;
  __syncthreads();
  dc[t] = ex;                          // reuse as cursor
  __syncthreads();
  for (int i = bstart + t; i < bend; i += 256){
    int p = tpack[i];
    int r = atomicAdd(&dc[p & 255], 1);
    csr[bstart + r] = p >> 8;
  }
}

// h[i] = x[i] + sum_{j in N(i)} x[j]   (unchanged; at fabric service floor)
__global__ __launch_bounds__(256) void agg_kernel(const __bf16* __restrict__ xb,
    const int* __restrict__ rs, const int* __restrict__ csr,
    __bf16* __restrict__ hb, int N)
{
  int node = blockIdx.x*4 + (threadIdx.x >> 6);
  if (node >= N) return;
  int lane = threadIdx.x & 63;
  int quad = lane >> 4;
  int l16  = lane & 15;
  int s = rs[node], e = rs[node+1];
  float a[8] = {0.f,0.f,0.f,0.f,0.f,0.f,0.f,0.f};
  for (int base = s; base < e; base += 64){
    int idx = base + lane;
    int nb = (idx < e) ? csr[idx] : 0;
    int cnt = e - base; if (cnt > 64) cnt = 64;
    int t = 0;
    #pragma unroll 2
    for (; t + 8 <= cnt; t += 8){
      int sA = __shfl(nb, t + quad);
      int sB = __shfl(nb, t + 4 + quad);
      bf16x8 vA = ((const bf16x8*)(xb + (long)sA*128))[l16];
      bf16x8 vB = ((const bf16x8*)(xb + (long)sB*128))[l16];
      #pragma unroll
      for (int j = 0; j < 8; j++) a[j] += (float)vA[j] + (float)vB[j];
    }
    for (; t < cnt; t += 4){
      int i = t + quad;
      int ic = (i < cnt) ? i : (cnt - 1);
      int sA = __shfl(nb, ic);
      bf16x8 vA = ((const bf16x8*)(xb + (long)sA*128))[l16];
      if (i < cnt){
        #pragma unroll
        for (int j = 0; j < 8; j++) a[j] += (float)vA[j];
      }
    }
  }
  if (quad == 0){
    bf16x8 sv = ((const bf16x8*)(xb + (long)node*128))[l16];
    #pragma unroll
    for (int j = 0; j < 8; j++) a[j] += (float)sv[j];
  }
  #pragma unroll
  for (int j = 0; j < 8; j++){
    a[j] += __shfl_xor(a[j], 16);
    a[j] += __shfl_xor(a[j], 32);
  }
  if (quad == 0){
    bf16x8 r;
    #pragma unroll
    for (int j = 0; j < 8; j++) r[j] = f2bf(a[j]);
    ((bf16x8*)(hb + (long)node*128))[l16] = r;
  }
}

// y_out[64-row tile] = ACT2( relu(A@W1 + b1) @ W2 + b2 + res )
// Residual prefetched at kernel start (latency hides under phase 1).
template<int ACT2>
__global__ __launch_bounds__(256, 4) void fused_mlp(const __bf16* __restrict__ A,
    const __bf16* __restrict__ wf1, const __bf16* __restrict__ wf2,
    const float* __restrict__ b1, const float* __restrict__ b2,
    const __bf16* __restrict__ res, __bf16* __restrict__ out, int M)
{
  __shared__ __bf16 H[64*128];
  int lane = threadIdx.x & 63;
  int wid = threadIdx.x >> 6;
  int quad = lane >> 4;
  long row0 = (long)blockIdx.x * 64;
  int col0 = wid*32 + (lane & 15);
  // prefetch residual for the whole tile (pure f(blockIdx); off critical path)
  float rv[4][2][4];
  #pragma unroll
  for (int rt = 0; rt < 4; rt++)
    #pragma unroll
    for (int c2 = 0; c2 < 2; c2++)
      #pragma unroll
      for (int i = 0; i < 4; i++){
        long orow = row0 + rt*16 + (quad << 2) + i;
        rv[rt][c2][i] = (orow < M) ? (float)res[orow*128 + col0 + c2*16] : 0.f;
      }
  const bf16x8* w1v = (const bf16x8*)wf1;
  const bf16x8* w2v = (const bf16x8*)wf2;
  bf16x8 bv1[2][4], bv2[2][4];
  #pragma unroll
  for (int c2 = 0; c2 < 2; c2++)
    #pragma unroll
    for (int ks = 0; ks < 4; ks++){
      bv1[c2][ks] = w1v[((wid*2 + c2)*4 + ks)*64 + lane];
      bv2[c2][ks] = w2v[((wid*2 + c2)*4 + ks)*64 + lane];
    }
  float bb1_0 = b1[col0], bb1_1 = b1[col0 + 16];
  float bb2_0 = b2[col0], bb2_1 = b2[col0 + 16];
  int koff = quad << 3;
  // phase 1: H = relu(A@W1 + b1)
  #pragma unroll 2
  for (int rt = 0; rt < 4; rt++){
    long row = row0 + rt*16 + (lane & 15);
    long rowc = (row < M) ? row : (long)(M-1);
    const __bf16* ap = A + rowc*128 + koff;
    bf16x8 av[4];
    #pragma unroll
    for (int ks = 0; ks < 4; ks++)
      av[ks] = *(const bf16x8*)(ap + ks*32);
    f32x4 acc0 = {0.f,0.f,0.f,0.f}, acc1 = {0.f,0.f,0.f,0.f};
    #pragma unroll
    for (int ks = 0; ks < 4; ks++){
      acc0 = __builtin_amdgcn_mfma_f32_16x16x32_bf16(av[ks], bv1[0][ks], acc0, 0, 0, 0);
      acc1 = __builtin_amdgcn_mfma_f32_16x16x32_bf16(av[ks], bv1[1][ks], acc1, 0, 0, 0);
    }
    int r0 = rt*16 + (quad << 2);
    #pragma unroll
    for (int c2 = 0; c2 < 2; c2++){
      f32x4 acc = c2 ? acc1 : acc0;
      int col = col0 + c2*16;
      float bb = c2 ? bb1_1 : bb1_0;
      #pragma unroll
      for (int i = 0; i < 4; i++)
        H[hswz(r0 + i, col)] = f2bf(fmaxf(acc[i] + bb, 0.f));
    }
  }
  __syncthreads();
  // phase 2: out = ACT2(H@W2 + b2 + rv)
  #pragma unroll 2
  for (int rt = 0; rt < 4; rt++){
    int r = rt*16 + (lane & 15);
    bf16x8 av[4];
    #pragma unroll
    for (int ks = 0; ks < 4; ks++)
      av[ks] = *(const bf16x8*)hvec(H, r, 4*ks + quad);
    f32x4 acc0 = {0.f,0.f,0.f,0.f}, acc1 = {0.f,0.f,0.f,0.f};
    #pragma unroll
    for (int ks = 0; ks < 4; ks++){
      acc0 = __builtin_amdgcn_mfma_f32_16x16x32_bf16(av[ks], bv2[0][ks], acc0, 0, 0, 0);
      acc1 = __builtin_amdgcn_mfma_f32_16x16x32_bf16(av[ks], bv2[1][ks], acc1, 0, 0, 0);
    }
    long orow0 = row0 + rt*16 + (quad << 2);
    #pragma unroll
    for (int c2 = 0; c2 < 2; c2++){
      f32x4 acc = c2 ? acc1 : acc0;
      int col = col0 + c2*16;
      float bb = c2 ? bb2_1 : bb2_0;
      #pragma unroll
      for (int i = 0; i < 4; i++){
        long orow = orow0 + i;
        if (orow < M){
          float v = acc[i] + bb + rv[rt][c2][i];
          if (ACT2 == 2) v = (v > 0.f) ? v : (__expf(v) - 1.f);
          out[orow*128 + col] = f2bf(v);
        }
      }
    }
  }
}

// Layer-3 MLP + JK projection, 64-row blocks, 16KB LDS (H reused for Y3).
// y2 residual prefetched at start; phase 2 uses held accumulators with ONE
// barrier between all LDS reads and all writes (was 4 in-loop barriers).
__global__ __launch_bounds__(256, 3) void fused_mlp_jk(const __bf16* __restrict__ A,
    const __bf16* __restrict__ y1g, const __bf16* __restrict__ y2g,
    const __bf16* __restrict__ wf1, const __bf16* __restrict__ wf2,
    const __bf16* __restrict__ wfjk,
    const float* __restrict__ b1, const float* __restrict__ b2,
    const float* __restrict__ jkb, float* __restrict__ out, int M)
{
  __shared__ __bf16 H[64*128];
  int lane = threadIdx.x & 63;
  int wid = threadIdx.x >> 6;
  int quad = lane >> 4;
  long row0 = (long)blockIdx.x * 64;
  int col0 = wid*32 + (lane & 15);
  // prefetch y2 residual for the whole tile
  float rv[4][2][4];
  #pragma unroll
  for (int rt = 0; rt < 4; rt++)
    #pragma unroll
    for (int c2 = 0; c2 < 2; c2++)
      #pragma unroll
      for (int i = 0; i < 4; i++){
        long orow = row0 + rt*16 + (quad << 2) + i;
        rv[rt][c2][i] = (orow < M) ? (float)y2g[orow*128 + col0 + c2*16] : 0.f;
      }
  const bf16x8* w1v = (const bf16x8*)wf1;
  const bf16x8* w2v = (const bf16x8*)wf2;
  bf16x8 bv1[2][4], bv2[2][4];
  #pragma unroll
  for (int c2 = 0; c2 < 2; c2++)
    #pragma unroll
    for (int ks = 0; ks < 4; ks++){
      bv1[c2][ks] = w1v[((wid*2 + c2)*4 + ks)*64 + lane];
      bv2[c2][ks] = w2v[((wid*2 + c2)*4 + ks)*64 + lane];
    }
  float bb1_0 = b1[col0], bb1_1 = b1[col0 + 16];
  float bb2_0 = b2[col0], bb2_1 = b2[col0 + 16];
  int koff = quad << 3;
  // phase 1: H = relu(A@W1 + b1)
  #pragma unroll 2
  for (int rt = 0; rt < 4; rt++){
    long row = row0 + rt*16 + (lane & 15);
    long rowc = (row < M) ? row : (long)(M-1);
    const __bf16* ap = A + rowc*128 + koff;
    bf16x8 av[4];
    #pragma unroll
    for (int ks = 0; ks < 4; ks++)
      av[ks] = *(const bf16x8*)(ap + ks*32);
    f32x4 acc0 = {0.f,0.f,0.f,0.f}, acc1 = {0.f,0.f,0.f,0.f};
    #pragma unroll
    for (int ks = 0; ks < 4; ks++){
      acc0 = __builtin_amdgcn_mfma_f32_16x16x32_bf16(av[ks], bv1[0][ks], acc0, 0, 0, 0);
      acc1 = __builtin_amdgcn_mfma_f32_16x16x32_bf16(av[ks], bv1[1][ks], acc1, 0, 0, 0);
    }
    int r0 = rt*16 + (quad << 2);
    #pragma unroll
    for (int c2 = 0; c2 < 2; c2++){
      f32x4 acc = c2 ? acc1 : acc0;
      int col = col0 + c2*16;
      float bb = c2 ? bb1_1 : bb1_0;
      #pragma unroll
      for (int i = 0; i < 4; i++)
        H[hswz(r0 + i, col)] = f2bf(fmaxf(acc[i] + bb, 0.f));
    }
  }
  __syncthreads();
  // phase 2: Y3 = H@W2 + b2 + y2, in place. All reads+MFMA -> ONE barrier -> writes.
  f32x4 acc2[4][2];
  #pragma unroll
  for (int rt = 0; rt < 4; rt++){
    int r = rt*16 + (lane & 15);
    bf16x8 av[4];
    #pragma unroll
    for (int ks = 0; ks < 4; ks++)
      av[ks] = *(const bf16x8*)hvec(H, r, 4*ks + quad);
    acc2[rt][0] = (f32x4){0.f,0.f,0.f,0.f};
    acc2[rt][1] = (f32x4){0.f,0.f,0.f,0.f};
    #pragma unroll
    for (int ks = 0; ks < 4; ks++){
      acc2[rt][0] = __builtin_amdgcn_mfma_f32_16x16x32_bf16(av[ks], bv2[0][ks], acc2[rt][0], 0, 0, 0);
      acc2[rt][1] = __builtin_amdgcn_mfma_f32_16x16x32_bf16(av[ks], bv2[1][ks], acc2[rt][1], 0, 0, 0);
    }
  }
  __syncthreads();    // all LDS reads complete before any overwrite
  #pragma unroll
  for (int rt = 0; rt < 4; rt++){
    int r0 = rt*16 + (quad << 2);
    #pragma unroll
    for (int c2 = 0; c2 < 2; c2++){
      int col = col0 + c2*16;
      float bb = c2 ? bb2_1 : bb2_0;
      #pragma unroll
      for (int i = 0; i < 4; i++)
        H[hswz(r0 + i, col)] = f2bf(acc2[rt][c2][i] + bb + rv[rt][c2][i]);
    }
  }
  __syncthreads();
  // phase 3: out = [y1|y2|Y3(=H)] @ jkW + jkb  (fp32), src-major, single pass
  const bf16x8* wjv = (const bf16x8*)wfjk;
  float jb0 = jkb[col0], jb1 = jkb[col0 + 16];
  f32x4 acc[4][2];
  #pragma unroll
  for (int q = 0; q < 4; q++){
    acc[q][0] = (f32x4){jb0, jb0, jb0, jb0};
    acc[q][1] = (f32x4){jb1, jb1, jb1, jb1};
  }
  #pragma unroll 1
  for (int src = 0; src < 2; src++){   // y1, y2 from global
    const __bf16* yg = src ? y2g : y1g;
    bf16x8 bv[2][4];
    #pragma unroll
    for (int c2 = 0; c2 < 2; c2++)
      #pragma unroll
      for (int ks = 0; ks < 4; ks++)
        bv[c2][ks] = wjv[(size_t)src*2048 + (size_t)((wid*2 + c2)*4 + ks)*64 + lane];
    #pragma unroll
    for (int q = 0; q < 4; q++){
      long row = row0 + q*16 + (lane & 15);
      long rowc = (row < M) ? row : (long)(M-1);
      const __bf16* ap = yg + rowc*128 + koff;
      bf16x8 av[4];
      #pragma unroll
      for (int ks = 0; ks < 4; ks++)
        av[ks] = *(const bf16x8*)(ap + ks*32);
      #pragma unroll
      for (int ks = 0; ks < 4; ks++){
        acc[q][0] = __builtin_amdgcn_mfma_f32_16x16x32_bf16(av[ks], bv[0][ks], acc[q][0], 0, 0, 0);
        acc[q][1] = __builtin_amdgcn_mfma_f32_16x16x32_bf16(av[ks], bv[1][ks], acc[q][1], 0, 0, 0);
      }
    }
  }
  {   // src 2: Y3 from LDS
    bf16x8 bv[2][4];
    #pragma unroll
    for (int c2 = 0; c2 < 2; c2++)
      #pragma unroll
      for (int ks = 0; ks < 4; ks++)
        bv[c2][ks] = wjv[(size_t)2*2048 + (size_t)((wid*2 + c2)*4 + ks)*64 + lane];
    #pragma unroll
    for (int q = 0; q < 4; q++){
      int r = q*16 + (lane & 15);
      bf16x8 av[4];
      #pragma unroll
      for (int ks = 0; ks < 4; ks++)
        av[ks] = *(const bf16x8*)hvec(H, r, 4*ks + quad);
      #pragma unroll
      for (int ks = 0; ks < 4; ks++){
        acc[q][0] = __builtin_amdgcn_mfma_f32_16x16x32_bf16(av[ks], bv[0][ks], acc[q][0], 0, 0, 0);
        acc[q][1] = __builtin_amdgcn_mfma_f32_16x16x32_bf16(av[ks], bv[1][ks], acc[q][1], 0, 0, 0);
      }
    }
  }
  #pragma unroll
  for (int q = 0; q < 4; q++){
    long orow0 = row0 + q*16 + (quad << 2);
    #pragma unroll
    for (int c2 = 0; c2 < 2; c2++){
      int col = col0 + c2*16;
      #pragma unroll
      for (int i = 0; i < 4; i++){
        long orow = orow0 + i;
        if (orow < M)
          out[orow*128 + col] = acc[q][c2][i];
      }
    }
  }
}

extern "C" void kernel_launch(void* const* d_in, const int* in_sizes, int n_in,
                              void* d_out, int out_size, void* d_ws, size_t ws_size,
                              hipStream_t stream)
{
  const float* x   = (const float*)d_in[0];
  const int*   ei  = (const int*)d_in[1];
  const float* w1[3] = {(const float*)d_in[2], (const float*)d_in[6], (const float*)d_in[10]};
  const float* b1[3] = {(const float*)d_in[3], (const float*)d_in[7], (const float*)d_in[11]};
  const float* w2[3] = {(const float*)d_in[4], (const float*)d_in[8], (const float*)d_in[12]};
  const float* b2[3] = {(const float*)d_in[5], (const float*)d_in[9], (const float*)d_in[13]};
  const float* jkw = (const float*)d_in[14];
  const float* jkb = (const float*)d_in[15];
  int N = in_sizes[0] / 128;
  int E = in_sizes[1] / 2;
  float* outp = (float*)d_out;

  char* wptr = (char*)d_ws;
  auto alloc = [&](size_t bytes)->void*{
    void* p = (void*)wptr; wptr += (bytes + 255) & ~(size_t)255; return p;
  };
  int NBLK = (E + CHUNK - 1) / CHUNK;          // 391
  int L = NBUCK * NBLK;                        // 200K
  int* rs    = (int*)alloc((size_t)(N+1)*4);
  int* csr   = (int*)alloc((size_t)E*4);
  int* tpack = (int*)alloc((size_t)E*4);
  int* cnt   = (int*)alloc((size_t)L*4);
  int* off   = (int*)alloc((size_t)L*4);
  __bf16* y[3];
  for (int i = 0; i < 3; i++) y[i] = (__bf16*)alloc((size_t)N*128*2);
  __bf16* hb = (__bf16*)alloc((size_t)N*128*2);
  __bf16* wf = (__bf16*)alloc((size_t)9*16384*2);
  int nsb = (L + 2047) / 2048;                 // scan blocks (98)
  int* bsum = (int*)alloc((size_t)nsb*4);
  int* boff = (int*)alloc((size_t)nsb*4);

  WPack pk;
  pk.p[0] = w1[0]; pk.p[1] = w2[0];
  pk.p[2] = w1[1]; pk.p[3] = w2[1];
  pk.p[4] = w1[2]; pk.p[5] = w2[2];
  pk.p[6] = jkw; pk.p[7] = jkw + 16384; pk.p[8] = jkw + 32768;
  int n8 = N*128/8;
  prep_kernel<<<576 + (n8 + 255)/256, 256, 0, stream>>>(pk, wf, x, y[0], n8);

  p1_count<<<NBLK, 256, 0, stream>>>(ei, E, NBLK, cnt);
  scan1_kernel<<<nsb, 256, 0, stream>>>(cnt, bsum, L);
  scan2_kernel<<<1, 256, 0, stream>>>(bsum, boff, nsb, rs + N);   // rs[N] = E
  scan3_kernel<<<nsb, 256, 0, stream>>>(cnt, boff, off, L);
  p3_scatter<<<NBLK, 256, 0, stream>>>(ei, E, NBLK, off, tpack);
  p4_build<<<NBUCK, 256, 0, stream>>>(tpack, off, NBLK, E, N, rs, csr);

  int gemm_blocks = (N + 63)/64;
  for (int l = 0; l < 3; l++){
    agg_kernel<<<(N + 3)/4, 256, 0, stream>>>(y[l], rs, csr, hb, N);
    if (l < 2)
      fused_mlp<2><<<gemm_blocks, 256, 0, stream>>>(hb, wf + (size_t)(2*l)*16384, wf + (size_t)(2*l+1)*16384,
                                                    b1[l], b2[l], y[l], y[l+1], N);
    else
      fused_mlp_jk<<<gemm_blocks, 256, 0, stream>>>(hb, y[1], y[2],
                                                    wf + (size_t)4*16384, wf + (size_t)5*16384, wf + (size_t)6*16384,
                                                    b1[2], b2[2], jkb, outp, N);
  }
}

// Round 12
// 358.156 us; speedup vs baseline: 1.2337x; 1.2337x over previous
//
#include <hip/hip_runtime.h>

typedef __bf16 bf16x8 __attribute__((ext_vector_type(8)));
typedef float f32x4 __attribute__((ext_vector_type(4)));

#define CHUNK 4096
#define NBUCK 512

struct WPack { const float* p[9]; };

__device__ inline __bf16 f2bf(float f){ return (__bf16)f; }

// Swizzled 64x128 bf16 LDS tile (16KB, no pad). Element (r,c) lives at
// r*128 + (((c>>3) ^ (r&7))<<3) + (c&7).
__device__ inline int hswz(int r, int c){
  return (r << 7) + ((((c >> 3) ^ (r & 7)) << 3) | (c & 7));
}
__device__ inline const __bf16* hvec(const __bf16* H, int r, int g){  // g = 8-elem granule 0..15
  return H + (r << 7) + (((g ^ (r & 7)) & 15) << 3);
}

// Combined prep: blocks [0,576) convert 9 fp32 128x128 weight mats into MFMA
// B-fragment layout (bf16); blocks [576,...) bulk-convert x fp32->bf16.
__global__ __launch_bounds__(256) void prep_kernel(WPack pk, __bf16* __restrict__ wf,
    const float* __restrict__ x, __bf16* __restrict__ xb, int n8){
  int b = blockIdx.x, t = threadIdx.x;
  if (b < 576){
    int tid = b*256 + t;
    int m = tid >> 14;
    int r = tid & 16383;
    int j = r & 7;
    int lane = (r >> 3) & 63;
    int ks = (r >> 9) & 3;
    int c = r >> 11;
    int k = ks*32 + ((lane>>4)<<3) + j;
    int col = (c<<4) + (lane & 15);
    wf[tid] = f2bf(pk.p[m][k*128 + col]);
  } else {
    int i = (b - 576)*256 + t;
    if (i >= n8) return;
    f32x4 a = ((const f32x4*)x)[2*i];
    f32x4 bb = ((const f32x4*)x)[2*i+1];
    bf16x8 r;
    r[0]=f2bf(a[0]); r[1]=f2bf(a[1]); r[2]=f2bf(a[2]); r[3]=f2bf(a[3]);
    r[4]=f2bf(bb[0]); r[5]=f2bf(bb[1]); r[6]=f2bf(bb[2]); r[7]=f2bf(bb[3]);
    ((bf16x8*)xb)[i] = r;
  }
}

// ---- CSR build via two-level bucket sort (no global atomics) ----
__global__ __launch_bounds__(256) void p1_count(const int* __restrict__ ei, int E, int NBLK,
    int* __restrict__ cnt){
  __shared__ int h[NBUCK];
  int b = blockIdx.x, t = threadIdx.x;
  h[t] = 0; h[t + 256] = 0;
  __syncthreads();
  int base = b*CHUNK;
  int lim = E - base; if (lim > CHUNK) lim = CHUNK;
  for (int i = t; i < lim; i += 256)
    atomicAdd(&h[ei[E + base + i] >> 8], 1);     // dst row
  __syncthreads();
  cnt[t*NBLK + b] = h[t];
  cnt[(t + 256)*NBLK + b] = h[t + 256];
}

__global__ __launch_bounds__(256) void scan1_kernel(const int* __restrict__ cnt, int* __restrict__ bsum, int L){
  __shared__ int sh[256];
  int b = blockIdx.x, t = threadIdx.x;
  int base = b*2048 + t*8;
  int s = 0;
  #pragma unroll
  for (int j = 0; j < 8; j++){ int i = base + j; if (i < L) s += cnt[i]; }
  sh[t] = s; __syncthreads();
  for (int off = 128; off > 0; off >>= 1){
    if (t < off) sh[t] += sh[t + off];
    __syncthreads();
  }
  if (t == 0) bsum[b] = sh[0];
}

__global__ __launch_bounds__(256) void scan2_kernel(const int* __restrict__ bsum, int* __restrict__ boff,
                                                    int NB, int* __restrict__ total_out){
  __shared__ int sh[256];
  int t = threadIdx.x;
  int v = (t < NB) ? bsum[t] : 0;
  sh[t] = v; __syncthreads();
  for (int off = 1; off < 256; off <<= 1){
    int u = (t >= off) ? sh[t - off] : 0;
    __syncthreads();
    sh[t] += u;
    __syncthreads();
  }
  if (t < NB) boff[t] = sh[t] - v;          // exclusive
  if (t == 255) *total_out = sh[255];       // rs[N] = E
}

__global__ __launch_bounds__(256) void scan3_kernel(const int* __restrict__ cnt, const int* __restrict__ boff,
                                                    int* __restrict__ off, int L){
  __shared__ int sh[256];
  int b = blockIdx.x, t = threadIdx.x;
  int base = b*2048 + t*8;
  int loc[8]; int s = 0;
  #pragma unroll
  for (int j = 0; j < 8; j++){ int i = base + j; int d = (i < L) ? cnt[i] : 0; loc[j] = d; s += d; }
  sh[t] = s; __syncthreads();
  for (int o = 1; o < 256; o <<= 1){
    int u = (t >= o) ? sh[t - o] : 0;
    __syncthreads();
    sh[t] += u;
    __syncthreads();
  }
  int excl = boff[b] + sh[t] - s;
  #pragma unroll
  for (int j = 0; j < 8; j++){ int i = base + j; if (i < L) off[i] = excl; excl += loc[j]; }
}

__global__ __launch_bounds__(256) void p3_scatter(const int* __restrict__ ei, int E, int NBLK,
    const int* __restrict__ off, int* __restrict__ tpack){
  __shared__ int cur[NBUCK];
  int b = blockIdx.x, t = threadIdx.x;
  cur[t]       = off[t*NBLK + b];
  cur[t + 256] = off[(t + 256)*NBLK + b];
  __syncthreads();
  int base = b*CHUNK;
  int lim = E - base; if (lim > CHUNK) lim = CHUNK;
  for (int i = t; i < lim; i += 256){
    int s = ei[base + i];
    int d = ei[E + base + i];
    int p = atomicAdd(&cur[d >> 8], 1);   // LDS atomic: global slot
    tpack[p] = (s << 8) | (d & 255);
  }
}

__global__ __launch_bounds__(256) void p4_build(const int* __restrict__ tpack,
    const int* __restrict__ off, int NBLK, int E, int N,
    int* __restrict__ rs, int* __restrict__ csr){
  __shared__ int dc[256], sc[256];
  int q = blockIdx.x, t = threadIdx.x;
  int bstart = off[q*NBLK];
  int bend = (q == NBUCK-1) ? E : off[(q+1)*NBLK];
  dc[t] = 0;
  __syncthreads();
  for (int i = bstart + t; i < bend; i += 256)
    atomicAdd(&dc[tpack[i] & 255], 1);
  __syncthreads();
  int v = dc[t];
  sc[t] = v; __syncthreads();
  for (int o = 1; o < 256; o <<= 1){
    int u = (t >= o) ? sc[t - o] : 0;
    __syncthreads();
    sc[t] += u;
    __syncthreads();
  }
  int ex = sc[t] - v;                  // exclusive within bucket
  int gd = q*256 + t;
  if (gd < N) rs[gd] = bstart + ex;
  __syncthreads();
  dc[t] = ex;                          // reuse as cursor
  __syncthreads();
  for (int i = bstart + t; i < bend; i += 256){
    int p = tpack[i];
    int r = atomicAdd(&dc[p & 255], 1);
    csr[bstart + r] = p >> 8;
  }
}

// h[i] = x[i] + sum_{j in N(i)} x[j]   (unchanged; at fabric service floor)
__global__ __launch_bounds__(256) void agg_kernel(const __bf16* __restrict__ xb,
    const int* __restrict__ rs, const int* __restrict__ csr,
    __bf16* __restrict__ hb, int N)
{
  int node = blockIdx.x*4 + (threadIdx.x >> 6);
  if (node >= N) return;
  int lane = threadIdx.x & 63;
  int quad = lane >> 4;
  int l16  = lane & 15;
  int s = rs[node], e = rs[node+1];
  float a[8] = {0.f,0.f,0.f,0.f,0.f,0.f,0.f,0.f};
  for (int base = s; base < e; base += 64){
    int idx = base + lane;
    int nb = (idx < e) ? csr[idx] : 0;
    int cnt = e - base; if (cnt > 64) cnt = 64;
    int t = 0;
    #pragma unroll 2
    for (; t + 8 <= cnt; t += 8){
      int sA = __shfl(nb, t + quad);
      int sB = __shfl(nb, t + 4 + quad);
      bf16x8 vA = ((const bf16x8*)(xb + (long)sA*128))[l16];
      bf16x8 vB = ((const bf16x8*)(xb + (long)sB*128))[l16];
      #pragma unroll
      for (int j = 0; j < 8; j++) a[j] += (float)vA[j] + (float)vB[j];
    }
    for (; t < cnt; t += 4){
      int i = t + quad;
      int ic = (i < cnt) ? i : (cnt - 1);
      int sA = __shfl(nb, ic);
      bf16x8 vA = ((const bf16x8*)(xb + (long)sA*128))[l16];
      if (i < cnt){
        #pragma unroll
        for (int j = 0; j < 8; j++) a[j] += (float)vA[j];
      }
    }
  }
  if (quad == 0){
    bf16x8 sv = ((const bf16x8*)(xb + (long)node*128))[l16];
    #pragma unroll
    for (int j = 0; j < 8; j++) a[j] += (float)sv[j];
  }
  #pragma unroll
  for (int j = 0; j < 8; j++){
    a[j] += __shfl_xor(a[j], 16);
    a[j] += __shfl_xor(a[j], 32);
  }
  if (quad == 0){
    bf16x8 r;
    #pragma unroll
    for (int j = 0; j < 8; j++) r[j] = f2bf(a[j]);
    ((bf16x8*)(hb + (long)node*128))[l16] = r;
  }
}

// y_out[64-row tile] = ACT2( relu(A@W1 + b1) @ W2 + b2 + res )
// Residual loaded per-rt at the top of the phase-2 iteration (overlaps the
// LDS reads + MFMAs of the same iteration; short reuse distance keeps L2 hot).
template<int ACT2>
__global__ __launch_bounds__(256, 4) void fused_mlp(const __bf16* __restrict__ A,
    const __bf16* __restrict__ wf1, const __bf16* __restrict__ wf2,
    const float* __restrict__ b1, const float* __restrict__ b2,
    const __bf16* __restrict__ res, __bf16* __restrict__ out, int M)
{
  __shared__ __bf16 H[64*128];
  int lane = threadIdx.x & 63;
  int wid = threadIdx.x >> 6;
  int quad = lane >> 4;
  long row0 = (long)blockIdx.x * 64;
  const bf16x8* w1v = (const bf16x8*)wf1;
  const bf16x8* w2v = (const bf16x8*)wf2;
  bf16x8 bv1[2][4], bv2[2][4];
  #pragma unroll
  for (int c2 = 0; c2 < 2; c2++)
    #pragma unroll
    for (int ks = 0; ks < 4; ks++){
      bv1[c2][ks] = w1v[((wid*2 + c2)*4 + ks)*64 + lane];
      bv2[c2][ks] = w2v[((wid*2 + c2)*4 + ks)*64 + lane];
    }
  int col0 = wid*32 + (lane & 15);
  float bb1_0 = b1[col0], bb1_1 = b1[col0 + 16];
  float bb2_0 = b2[col0], bb2_1 = b2[col0 + 16];
  int koff = quad << 3;
  // phase 1: H = relu(A@W1 + b1)
  #pragma unroll 2
  for (int rt = 0; rt < 4; rt++){
    long row = row0 + rt*16 + (lane & 15);
    long rowc = (row < M) ? row : (long)(M-1);
    const __bf16* ap = A + rowc*128 + koff;
    bf16x8 av[4];
    #pragma unroll
    for (int ks = 0; ks < 4; ks++)
      av[ks] = *(const bf16x8*)(ap + ks*32);
    f32x4 acc0 = {0.f,0.f,0.f,0.f}, acc1 = {0.f,0.f,0.f,0.f};
    #pragma unroll
    for (int ks = 0; ks < 4; ks++){
      acc0 = __builtin_amdgcn_mfma_f32_16x16x32_bf16(av[ks], bv1[0][ks], acc0, 0, 0, 0);
      acc1 = __builtin_amdgcn_mfma_f32_16x16x32_bf16(av[ks], bv1[1][ks], acc1, 0, 0, 0);
    }
    int r0 = rt*16 + (quad << 2);
    #pragma unroll
    for (int c2 = 0; c2 < 2; c2++){
      f32x4 acc = c2 ? acc1 : acc0;
      int col = col0 + c2*16;
      float bb = c2 ? bb1_1 : bb1_0;
      #pragma unroll
      for (int i = 0; i < 4; i++)
        H[hswz(r0 + i, col)] = f2bf(fmaxf(acc[i] + bb, 0.f));
    }
  }
  __syncthreads();
  // phase 2: out = ACT2(H@W2 + b2 + res)
  #pragma unroll 2
  for (int rt = 0; rt < 4; rt++){
    // issue residual loads for this rt first (overlap with LDS reads + MFMA)
    float rv[2][4];
    #pragma unroll
    for (int c2 = 0; c2 < 2; c2++)
      #pragma unroll
      for (int i = 0; i < 4; i++){
        long orow = row0 + rt*16 + (quad << 2) + i;
        rv[c2][i] = (orow < M) ? (float)res[orow*128 + col0 + c2*16] : 0.f;
      }
    int r = rt*16 + (lane & 15);
    bf16x8 av[4];
    #pragma unroll
    for (int ks = 0; ks < 4; ks++)
      av[ks] = *(const bf16x8*)hvec(H, r, 4*ks + quad);
    f32x4 acc0 = {0.f,0.f,0.f,0.f}, acc1 = {0.f,0.f,0.f,0.f};
    #pragma unroll
    for (int ks = 0; ks < 4; ks++){
      acc0 = __builtin_amdgcn_mfma_f32_16x16x32_bf16(av[ks], bv2[0][ks], acc0, 0, 0, 0);
      acc1 = __builtin_amdgcn_mfma_f32_16x16x32_bf16(av[ks], bv2[1][ks], acc1, 0, 0, 0);
    }
    long orow0 = row0 + rt*16 + (quad << 2);
    #pragma unroll
    for (int c2 = 0; c2 < 2; c2++){
      f32x4 acc = c2 ? acc1 : acc0;
      int col = col0 + c2*16;
      float bb = c2 ? bb2_1 : bb2_0;
      #pragma unroll
      for (int i = 0; i < 4; i++){
        long orow = orow0 + i;
        if (orow < M){
          float v = acc[i] + bb + rv[c2][i];
          if (ACT2 == 2) v = (v > 0.f) ? v : (__expf(v) - 1.f);
          out[orow*128 + col] = f2bf(v);
        }
      }
    }
  }
}

// Layer-3 MLP + JK projection, 64-row blocks. Two 16KB LDS tiles:
// H (hidden, reused in place for Y3) and Y2L (y2 tile stashed as bf16 during
// the phase-2 residual loads, so phase 3 reads y2 from LDS — y2 touches
// global exactly once and the phase-3 global-latency chain drops to y1 only).
__global__ __launch_bounds__(256, 4) void fused_mlp_jk(const __bf16* __restrict__ A,
    const __bf16* __restrict__ y1g, const __bf16* __restrict__ y2g,
    const __bf16* __restrict__ wf1, const __bf16* __restrict__ wf2,
    const __bf16* __restrict__ wfjk,
    const float* __restrict__ b1, const float* __restrict__ b2,
    const float* __restrict__ jkb, float* __restrict__ out, int M)
{
  __shared__ __bf16 H[64*128];
  __shared__ __bf16 Y2L[64*128];
  int lane = threadIdx.x & 63;
  int wid = threadIdx.x >> 6;
  int quad = lane >> 4;
  long row0 = (long)blockIdx.x * 64;
  const bf16x8* w1v = (const bf16x8*)wf1;
  const bf16x8* w2v = (const bf16x8*)wf2;
  bf16x8 bv1[2][4], bv2[2][4];
  #pragma unroll
  for (int c2 = 0; c2 < 2; c2++)
    #pragma unroll
    for (int ks = 0; ks < 4; ks++){
      bv1[c2][ks] = w1v[((wid*2 + c2)*4 + ks)*64 + lane];
      bv2[c2][ks] = w2v[((wid*2 + c2)*4 + ks)*64 + lane];
    }
  int col0 = wid*32 + (lane & 15);
  float bb1_0 = b1[col0], bb1_1 = b1[col0 + 16];
  float bb2_0 = b2[col0], bb2_1 = b2[col0 + 16];
  int koff = quad << 3;
  // phase 1: H = relu(A@W1 + b1)
  #pragma unroll 2
  for (int rt = 0; rt < 4; rt++){
    long row = row0 + rt*16 + (lane & 15);
    long rowc = (row < M) ? row : (long)(M-1);
    const __bf16* ap = A + rowc*128 + koff;
    bf16x8 av[4];
    #pragma unroll
    for (int ks = 0; ks < 4; ks++)
      av[ks] = *(const bf16x8*)(ap + ks*32);
    f32x4 acc0 = {0.f,0.f,0.f,0.f}, acc1 = {0.f,0.f,0.f,0.f};
    #pragma unroll
    for (int ks = 0; ks < 4; ks++){
      acc0 = __builtin_amdgcn_mfma_f32_16x16x32_bf16(av[ks], bv1[0][ks], acc0, 0, 0, 0);
      acc1 = __builtin_amdgcn_mfma_f32_16x16x32_bf16(av[ks], bv1[1][ks], acc1, 0, 0, 0);
    }
    int r0 = rt*16 + (quad << 2);
    #pragma unroll
    for (int c2 = 0; c2 < 2; c2++){
      f32x4 acc = c2 ? acc1 : acc0;
      int col = col0 + c2*16;
      float bb = c2 ? bb1_1 : bb1_0;
      #pragma unroll
      for (int i = 0; i < 4; i++)
        H[hswz(r0 + i, col)] = f2bf(fmaxf(acc[i] + bb, 0.f));
    }
  }
  __syncthreads();
  // phase 2: H <- Y3 = H@W2 + b2 + y2  (in place; read tile -> barrier -> write)
  // y2 loaded per-rt (L2-hot) and also stashed into Y2L for phase 3.
  #pragma unroll 1
  for (int rt = 0; rt < 4; rt++){
    int r = rt*16 + (lane & 15);
    bf16x8 av[4];
    #pragma unroll
    for (int ks = 0; ks < 4; ks++)
      av[ks] = *(const bf16x8*)hvec(H, r, 4*ks + quad);
    f32x4 acc0 = {0.f,0.f,0.f,0.f}, acc1 = {0.f,0.f,0.f,0.f};
    #pragma unroll
    for (int ks = 0; ks < 4; ks++){
      acc0 = __builtin_amdgcn_mfma_f32_16x16x32_bf16(av[ks], bv2[0][ks], acc0, 0, 0, 0);
      acc1 = __builtin_amdgcn_mfma_f32_16x16x32_bf16(av[ks], bv2[1][ks], acc1, 0, 0, 0);
    }
    long orow0 = row0 + rt*16 + (quad << 2);
    int r0 = rt*16 + (quad << 2);
    __bf16 rb[2][4];
    #pragma unroll
    for (int c2 = 0; c2 < 2; c2++)
      #pragma unroll
      for (int i = 0; i < 4; i++){
        long orow = orow0 + i;
        rb[c2][i] = (orow < M) ? y2g[orow*128 + col0 + c2*16] : f2bf(0.f);
      }
    __syncthreads();    // all reads of tile rt done before overwrite
    #pragma unroll
    for (int c2 = 0; c2 < 2; c2++){
      f32x4 acc = c2 ? acc1 : acc0;
      int col = col0 + c2*16;
      float bb = c2 ? bb2_1 : bb2_0;
      #pragma unroll
      for (int i = 0; i < 4; i++){
        Y2L[hswz(r0 + i, col)] = rb[c2][i];
        H[hswz(r0 + i, col)] = f2bf(acc[i] + bb + (float)rb[c2][i]);
      }
    }
  }
  __syncthreads();
  // phase 3: out = [y1|Y2L|Y3(=H)] @ jkW + jkb  (fp32), src-major, single pass
  const bf16x8* wjv = (const bf16x8*)wfjk;
  float jb0 = jkb[col0], jb1 = jkb[col0 + 16];
  f32x4 acc[4][2];
  #pragma unroll
  for (int q = 0; q < 4; q++){
    acc[q][0] = (f32x4){jb0, jb0, jb0, jb0};
    acc[q][1] = (f32x4){jb1, jb1, jb1, jb1};
  }
  {   // src 0: y1 from global
    bf16x8 bv[2][4];
    #pragma unroll
    for (int c2 = 0; c2 < 2; c2++)
      #pragma unroll
      for (int ks = 0; ks < 4; ks++)
        bv[c2][ks] = wjv[(size_t)((wid*2 + c2)*4 + ks)*64 + lane];
    #pragma unroll
    for (int q = 0; q < 4; q++){
      long row = row0 + q*16 + (lane & 15);
      long rowc = (row < M) ? row : (long)(M-1);
      const __bf16* ap = y1g + rowc*128 + koff;
      bf16x8 av[4];
      #pragma unroll
      for (int ks = 0; ks < 4; ks++)
        av[ks] = *(const bf16x8*)(ap + ks*32);
      #pragma unroll
      for (int ks = 0; ks < 4; ks++){
        acc[q][0] = __builtin_amdgcn_mfma_f32_16x16x32_bf16(av[ks], bv[0][ks], acc[q][0], 0, 0, 0);
        acc[q][1] = __builtin_amdgcn_mfma_f32_16x16x32_bf16(av[ks], bv[1][ks], acc[q][1], 0, 0, 0);
      }
    }
  }
  #pragma unroll 1
  for (int src = 1; src < 3; src++){   // y2, y3 from LDS
    const __bf16* Hs = (src == 1) ? Y2L : H;
    bf16x8 bv[2][4];
    #pragma unroll
    for (int c2 = 0; c2 < 2; c2++)
      #pragma unroll
      for (int ks = 0; ks < 4; ks++)
        bv[c2][ks] = wjv[(size_t)src*2048 + (size_t)((wid*2 + c2)*4 + ks)*64 + lane];
    #pragma unroll
    for (int q = 0; q < 4; q++){
      int r = q*16 + (lane & 15);
      bf16x8 av[4];
      #pragma unroll
      for (int ks = 0; ks < 4; ks++)
        av[ks] = *(const bf16x8*)hvec(Hs, r, 4*ks + quad);
      #pragma unroll
      for (int ks = 0; ks < 4; ks++){
        acc[q][0] = __builtin_amdgcn_mfma_f32_16x16x32_bf16(av[ks], bv[0][ks], acc[q][0], 0, 0, 0);
        acc[q][1] = __builtin_amdgcn_mfma_f32_16x16x32_bf16(av[ks], bv[1][ks], acc[q][1], 0, 0, 0);
      }
    }
  }
  #pragma unroll
  for (int q = 0; q < 4; q++){
    long orow0 = row0 + q*16 + (quad << 2);
    #pragma unroll
    for (int c2 = 0; c2 < 2; c2++){
      int col = col0 + c2*16;
      #pragma unroll
      for (int i = 0; i < 4; i++){
        long orow = orow0 + i;
        if (orow < M)
          out[orow*128 + col] = acc[q][c2][i];
      }
    }
  }
}

extern "C" void kernel_launch(void* const* d_in, const int* in_sizes, int n_in,
                              void* d_out, int out_size, void* d_ws, size_t ws_size,
                              hipStream_t stream)
{
  const float* x   = (const float*)d_in[0];
  const int*   ei  = (const int*)d_in[1];
  const float* w1[3] = {(const float*)d_in[2], (const float*)d_in[6], (const float*)d_in[10]};
  const float* b1[3] = {(const float*)d_in[3], (const float*)d_in[7], (const float*)d_in[11]};
  const float* w2[3] = {(const float*)d_in[4], (const float*)d_in[8], (const float*)d_in[12]};
  const float* b2[3] = {(const float*)d_in[5], (const float*)d_in[9], (const float*)d_in[13]};
  const float* jkw = (const float*)d_in[14];
  const float* jkb = (const float*)d_in[15];
  int N = in_sizes[0] / 128;
  int E = in_sizes[1] / 2;
  float* outp = (float*)d_out;

  char* wptr = (char*)d_ws;
  auto alloc = [&](size_t bytes)->void*{
    void* p = (void*)wptr; wptr += (bytes + 255) & ~(size_t)255; return p;
  };
  int NBLK = (E + CHUNK - 1) / CHUNK;          // 391
  int L = NBUCK * NBLK;                        // 200K
  int* rs    = (int*)alloc((size_t)(N+1)*4);
  int* csr   = (int*)alloc((size_t)E*4);
  int* tpack = (int*)alloc((size_t)E*4);
  int* cnt   = (int*)alloc((size_t)L*4);
  int* off   = (int*)alloc((size_t)L*4);
  __bf16* y[3];
  for (int i = 0; i < 3; i++) y[i] = (__bf16*)alloc((size_t)N*128*2);
  __bf16* hb = (__bf16*)alloc((size_t)N*128*2);
  __bf16* wf = (__bf16*)alloc((size_t)9*16384*2);
  int nsb = (L + 2047) / 2048;                 // scan blocks (98)
  int* bsum = (int*)alloc((size_t)nsb*4);
  int* boff = (int*)alloc((size_t)nsb*4);

  WPack pk;
  pk.p[0] = w1[0]; pk.p[1] = w2[0];
  pk.p[2] = w1[1]; pk.p[3] = w2[1];
  pk.p[4] = w1[2]; pk.p[5] = w2[2];
  pk.p[6] = jkw; pk.p[7] = jkw + 16384; pk.p[8] = jkw + 32768;
  int n8 = N*128/8;
  prep_kernel<<<576 + (n8 + 255)/256, 256, 0, stream>>>(pk, wf, x, y[0], n8);

  p1_count<<<NBLK, 256, 0, stream>>>(ei, E, NBLK, cnt);
  scan1_kernel<<<nsb, 256, 0, stream>>>(cnt, bsum, L);
  scan2_kernel<<<1, 256, 0, stream>>>(bsum, boff, nsb, rs + N);   // rs[N] = E
  scan3_kernel<<<nsb, 256, 0, stream>>>(cnt, boff, off, L);
  p3_scatter<<<NBLK, 256, 0, stream>>>(ei, E, NBLK, off, tpack);
  p4_build<<<NBUCK, 256, 0, stream>>>(tpack, off, NBLK, E, N, rs, csr);

  int gemm_blocks = (N + 63)/64;
  for (int l = 0; l < 3; l++){
    agg_kernel<<<(N + 3)/4, 256, 0, stream>>>(y[l], rs, csr, hb, N);
    if (l < 2)
      fused_mlp<2><<<gemm_blocks, 256, 0, stream>>>(hb, wf + (size_t)(2*l)*16384, wf + (size_t)(2*l+1)*16384,
                                                    b1[l], b2[l], y[l], y[l+1], N);
    else
      fused_mlp_jk<<<gemm_blocks, 256, 0, stream>>>(hb, y[1], y[2],
                                                    wf + (size_t)4*16384, wf + (size_t)5*16384, wf + (size_t)6*16384,
                                                    b1[2], b2[2], jkb, outp, N);
  }
}